// Round 9
// baseline (466.482 us; speedup 1.0000x reference)
//
#include <hip/hip_runtime.h>
#include <hip/hip_bf16.h>

typedef __bf16 bf16x8 __attribute__((ext_vector_type(8)));
typedef __bf16 bf16x4 __attribute__((ext_vector_type(4)));
typedef float  f32x4  __attribute__((ext_vector_type(4)));

#define N_IN 1024
#define NTHR 512

#define RAW_BARRIER() do {                                      \
    asm volatile("s_waitcnt lgkmcnt(0)" ::: "memory");          \
    __builtin_amdgcn_s_barrier();                               \
    asm volatile("" ::: "memory");                              \
} while (0)

// ---------- kernel 0: B (fp32) -> bf16 ----------
__global__ void convB_kernel(const float* __restrict__ B, __bf16* __restrict__ Bb) {
    int i = blockIdx.x * blockDim.x + threadIdx.x;
    f32x4 v = ((const f32x4*)B)[i];
    bf16x4 o;
    o[0] = (__bf16)v[0]; o[1] = (__bf16)v[1]; o[2] = (__bf16)v[2]; o[3] = (__bf16)v[3];
    ((bf16x4*)Bb)[i] = o;
}

// ---------- kernel 1: O = num * avg^alpha (pure streaming) ----------
__global__ __launch_bounds__(256)
void pow_kernel(const float* __restrict__ x, const float* __restrict__ alpha,
                __bf16* __restrict__ O, int nvec) {
    for (int v = blockIdx.x * blockDim.x + threadIdx.x; v < nvec;
         v += gridDim.x * blockDim.x) {
        int row = v >> 7;
        int k   = (v & 127) << 3;
        const float* xr = x + (long)row * (2 * N_IN);
        f32x4 a0 = __builtin_nontemporal_load((const f32x4*)(xr + k));
        f32x4 a1 = __builtin_nontemporal_load((const f32x4*)(xr + k + 4));
        f32x4 n0 = __builtin_nontemporal_load((const f32x4*)(xr + N_IN + k));
        f32x4 n1 = __builtin_nontemporal_load((const f32x4*)(xr + N_IN + k + 4));
        f32x4 l0 = *(const f32x4*)(alpha + k);
        f32x4 l1 = *(const f32x4*)(alpha + k + 4);
        bf16x8 w;
        #pragma unroll
        for (int e = 0; e < 4; ++e) {
            w[e]     = (__bf16)(n0[e] * __expf(l0[e] * __logf(a0[e])));
            w[e + 4] = (__bf16)(n1[e] * __expf(l1[e] * __logf(a1[e])));
        }
        __builtin_nontemporal_store(w, (bf16x8*)(O + (long)row * N_IN + k));
    }
}

// ---------- kernel 2: 256x256x1024 tile GEMM + fused dot epilogue ----------
// A(o) K-streamed through 64KB double-buffered LDS (reg-staged, swizzled writes);
// B direct L2->reg, distance-2 prefetch; ONE raw barrier per K-tile, lgkmcnt only
// (vmcnt never drained -> B pipeline continuous). partial[colblk][b] written.
__global__ __launch_bounds__(NTHR, 2)
void qf_kernel(const __bf16* __restrict__ O, const __bf16* __restrict__ Bb,
               const float* __restrict__ A, float* __restrict__ partial, int batch) {
    __shared__ __align__(16) __bf16 atile[2][256 * 64];   // 64 KB
    __shared__ float rowsum[4][256];                       // 4 KB

    const int t0   = threadIdx.x;
    const int wave = t0 >> 6;
    const int lane = t0 & 63;
    const int lrow = lane & 15;
    const int lgrp = lane >> 4;
    const int wm   = wave >> 2;            // 0..1  (row half)
    const int wn   = wave & 3;             // 0..3  (col quarter)
    const int rowpanel = blockIdx.x & 255;
    const int colblk   = blockIdx.x >> 8;  // colblk-outer: row-sharers on same XCD
    const long blk_row = (long)rowpanel * 256;
    const int colbase  = colblk * 256 + wn * 64;

    // A-staging role: 2 threads per row, 4 granules (16B) each, 64B contiguous src
    const int srow = t0 >> 1;              // 0..255
    const int g0   = (t0 & 1) * 4;         // 0 or 4
    const int s7   = srow & 7;
    const __bf16* asrc = O + (blk_row + srow) * N_IN;

    const __bf16* bbase = Bb + (long)(colbase + lrow) * N_IN + lgrp * 8;

    f32x4 acc[8][4];
    #pragma unroll
    for (int m = 0; m < 8; ++m)
        #pragma unroll
        for (int n = 0; n < 4; ++n)
            acc[m][n] = f32x4{0.f, 0.f, 0.f, 0.f};

    bf16x8 b0[4], b1[4];
    auto loadB = [&](bf16x8* dst, int kc) {
        #pragma unroll
        for (int n = 0; n < 4; ++n)
            dst[n] = *(const bf16x8*)(bbase + (long)n * 16 * N_IN + kc * 32);
    };

    // ---- prologue: stage K-tile 0, prefetch B chunks 0,1 ----
    {
        bf16x8 s[4];
        #pragma unroll
        for (int u = 0; u < 4; ++u)
            s[u] = *(const bf16x8*)(asrc + (g0 + u) * 8);
        #pragma unroll
        for (int u = 0; u < 4; ++u)
            *(bf16x8*)&atile[0][srow * 64 + (((g0 + u) ^ s7) << 3)] = s[u];
    }
    loadB(b0, 0);
    loadB(b1, 1);
    RAW_BARRIER();

    // ---- main loop: 16 K-tiles of 64, one raw barrier per tile ----
    #pragma unroll 1
    for (int t = 0; t < 16; ++t) {
        const int ts = (t + 1 < 16) ? t + 1 : 15;   // tail re-reads tile 15
        bf16x8 s[4];
        #pragma unroll
        for (int u = 0; u < 4; ++u)                  // issue early: HBM/L3 latency
            s[u] = *(const bf16x8*)(asrc + ts * 64 + (g0 + u) * 8);

        #pragma unroll
        for (int kq = 0; kq < 2; ++kq) {
            const int kc = 2 * t + kq;
            bf16x8* cur = kq ? b1 : b0;
            bf16x8 afr[8];
            #pragma unroll
            for (int m = 0; m < 8; ++m) {
                const int r  = wm * 128 + m * 16 + lrow;
                const int gg = kq * 4 + lgrp;
                afr[m] = *(const bf16x8*)&atile[t & 1][r * 64 + ((gg ^ (r & 7)) << 3)];
            }
            #pragma unroll
            for (int m = 0; m < 8; ++m)
                #pragma unroll
                for (int n = 0; n < 4; ++n)
                    acc[m][n] = __builtin_amdgcn_mfma_f32_16x16x32_bf16(
                        afr[m], cur[n], acc[m][n], 0, 0, 0);
            if (kc + 2 < 32) loadB(cur, kc + 2);     // dist-2, stays in flight
        }

        // late write of staged tile t+1 (compiler waits vmcnt for s only)
        #pragma unroll
        for (int u = 0; u < 4; ++u)
            *(bf16x8*)&atile[(t + 1) & 1][srow * 64 + (((g0 + u) ^ s7) << 3)] = s[u];
        RAW_BARRIER();
    }

    // ---- epilogue: rp[r] = sum_{i in colblk} (Y[r][i] + A[i]) * o[r][i] ----
    float rp[32];
    #pragma unroll
    for (int i = 0; i < 32; ++i) rp[i] = 0.f;
    #pragma unroll
    for (int n = 0; n < 4; ++n) {
        const int i = colbase + n * 16 + lrow;
        const float Ai = A[i];
        #pragma unroll
        for (int m = 0; m < 8; ++m)
            #pragma unroll
            for (int j = 0; j < 4; ++j) {
                const long r = blk_row + wm * 128 + m * 16 + lgrp * 4 + j;
                float ov = (float)O[r * N_IN + i];   // L2/L3-hot (just staged)
                rp[m * 4 + j] += (acc[m][n][j] + Ai) * ov;
            }
    }
    #pragma unroll
    for (int d = 1; d < 16; d <<= 1)
        #pragma unroll
        for (int i = 0; i < 32; ++i)
            rp[i] += __shfl_xor(rp[i], d);
    if (lrow == 0) {
        #pragma unroll
        for (int m = 0; m < 8; ++m)
            #pragma unroll
            for (int j = 0; j < 4; ++j)
                rowsum[wn][wm * 128 + m * 16 + lgrp * 4 + j] = rp[m * 4 + j];
    }
    __syncthreads();
    if (t0 < 256) {
        float s = rowsum[0][t0] + rowsum[1][t0] + rowsum[2][t0] + rowsum[3][t0];
        partial[(long)colblk * batch + blk_row + t0] = s;
    }
}

// ---------- kernel 3: out = C + sum_c partial[c] ----------
__global__ __launch_bounds__(256)
void reduce_kernel(const float* __restrict__ partial, const float* __restrict__ Cp,
                   float* __restrict__ out, int batch) {
    int b = (blockIdx.x * 256 + threadIdx.x) * 4;
    if (b >= batch) return;
    f32x4 s = *(const f32x4*)(partial + b);
    #pragma unroll
    for (int c = 1; c < 4; ++c) {
        f32x4 p = *(const f32x4*)(partial + (long)c * batch + b);
        s[0] += p[0]; s[1] += p[1]; s[2] += p[2]; s[3] += p[3];
    }
    float C = Cp[0];
    f32x4 o; o[0] = s[0] + C; o[1] = s[1] + C; o[2] = s[2] + C; o[3] = s[3] + C;
    *(f32x4*)(out + b) = o;
}

// ---------- fallback: round-2 fused kernel (used if ws too small) ----------
template<bool USEBF>
__global__ __launch_bounds__(NTHR, 2)
void fused_kernel(const float* __restrict__ x, const float* __restrict__ A,
                  const float* __restrict__ Bf, const __bf16* __restrict__ Bb,
                  const float* __restrict__ Cp, const float* __restrict__ alpha,
                  float* __restrict__ out) {
    __shared__ __align__(16) __bf16 o_panel[64 * N_IN];
    __shared__ float rowsum[8][64];
    const int t = threadIdx.x, wave = t >> 6, lane = t & 63;
    const int lrow = lane & 15, lgrp = lane >> 4;
    const long blk_row = (long)blockIdx.x * 64;
    const int srow = t >> 3, skoff = (t & 7) * 4;
    const float* xrow = x + (blk_row + srow) * (2 * N_IN);
    #pragma unroll
    for (int c = 0; c < 8; ++c) {
        int k = c * 32 + skoff;
        f32x4 sa = *(const f32x4*)(xrow + k);
        f32x4 sn = *(const f32x4*)(xrow + N_IN + k);
        f32x4 sal = *(const f32x4*)(alpha + k);
        bf16x4 w4;
        #pragma unroll
        for (int e = 0; e < 4; ++e)
            w4[e] = (__bf16)(sn[e] * __expf(sal[e] * __logf(sa[e])));
        *(bf16x4*)&o_panel[srow * N_IN + ((k & ~7) ^ ((srow & 7) << 3)) + (k & 7)] = w4;
    }
    __syncthreads();
    f32x4 acc[2][4][4];
    #pragma unroll
    for (int h = 0; h < 2; ++h)
        #pragma unroll
        for (int m = 0; m < 4; ++m)
            #pragma unroll
            for (int n = 0; n < 4; ++n)
                acc[h][m][n] = f32x4{0.f, 0.f, 0.f, 0.f};
    #pragma unroll 1
    for (int q = 0; q < 4; ++q) {
        #pragma unroll
        for (int kq = 0; kq < 8; ++kq) {
            const int kc = q * 8 + kq;
            const bool staging = (q < 3);
            const int kk = kc * 32 + lgrp * 8;
            f32x4 sa, sn, sal;
            if (staging) {
                int k = (kc + 8) * 32 + skoff;
                sa = *(const f32x4*)(xrow + k);
                sn = *(const f32x4*)(xrow + N_IN + k);
                sal = *(const f32x4*)(alpha + k);
            }
            bf16x8 afr[4];
            #pragma unroll
            for (int m = 0; m < 4; ++m) {
                int r = m * 16 + lrow;
                afr[m] = *(const bf16x8*)&o_panel[r * N_IN + (kk ^ ((r & 7) << 3))];
            }
            bf16x8 bfr[2][4];
            #pragma unroll
            for (int h = 0; h < 2; ++h)
                #pragma unroll
                for (int n = 0; n < 4; ++n) {
                    int i = h * 512 + wave * 64 + n * 16 + lrow;
                    if constexpr (USEBF) {
                        bfr[h][n] = *(const bf16x8*)&Bb[(long)i * N_IN + kk];
                    } else {
                        const float* p = Bf + (long)i * N_IN + kk;
                        f32x4 lo = *(const f32x4*)p;
                        f32x4 hi = *(const f32x4*)(p + 4);
                        #pragma unroll
                        for (int e = 0; e < 4; ++e) {
                            bfr[h][n][e] = (__bf16)lo[e];
                            bfr[h][n][e + 4] = (__bf16)hi[e];
                        }
                    }
                }
            #pragma unroll
            for (int h = 0; h < 2; ++h)
                #pragma unroll
                for (int m = 0; m < 4; ++m)
                    #pragma unroll
                    for (int n = 0; n < 4; ++n)
                        acc[h][m][n] = __builtin_amdgcn_mfma_f32_16x16x32_bf16(
                            afr[m], bfr[h][n], acc[h][m][n], 0, 0, 0);
            if (staging) {
                int k = (kc + 8) * 32 + skoff;
                bf16x4 w4;
                #pragma unroll
                for (int e = 0; e < 4; ++e)
                    w4[e] = (__bf16)(sn[e] * __expf(sal[e] * __logf(sa[e])));
                *(bf16x4*)&o_panel[srow * N_IN + ((k & ~7) ^ ((srow & 7) << 3)) + (k & 7)] = w4;
            }
        }
        __syncthreads();
    }
    float rowpart[16];
    #pragma unroll
    for (int i = 0; i < 16; ++i) rowpart[i] = 0.f;
    #pragma unroll
    for (int h = 0; h < 2; ++h)
        #pragma unroll
        for (int n = 0; n < 4; ++n) {
            int i = h * 512 + wave * 64 + n * 16 + lrow;
            float Ai = A[i];
            #pragma unroll
            for (int m = 0; m < 4; ++m)
                #pragma unroll
                for (int j = 0; j < 4; ++j) {
                    int r = m * 16 + lgrp * 4 + j;
                    float y = acc[h][m][n][j] + Ai;
                    float ov = (float)o_panel[r * N_IN + ((i & ~7) ^ ((r & 7) << 3)) + (i & 7)];
                    rowpart[m * 4 + j] += y * ov;
                }
        }
    #pragma unroll
    for (int d = 1; d < 16; d <<= 1)
        #pragma unroll
        for (int i = 0; i < 16; ++i)
            rowpart[i] += __shfl_xor(rowpart[i], d);
    if (lrow == 0) {
        #pragma unroll
        for (int m = 0; m < 4; ++m)
            #pragma unroll
            for (int j = 0; j < 4; ++j)
                rowsum[wave][m * 16 + lgrp * 4 + j] = rowpart[m * 4 + j];
    }
    __syncthreads();
    if (t < 64) {
        float s = Cp[0];
        #pragma unroll
        for (int w = 0; w < 8; ++w) s += rowsum[w][t];
        out[blk_row + t] = s;
    }
}

extern "C" void kernel_launch(void* const* d_in, const int* in_sizes, int n_in,
                              void* d_out, int out_size, void* d_ws, size_t ws_size,
                              hipStream_t stream) {
    const float* x     = (const float*)d_in[0];
    const float* A     = (const float*)d_in[1];
    const float* B     = (const float*)d_in[2];
    const float* C     = (const float*)d_in[3];
    const float* alpha = (const float*)d_in[4];
    float* out = (float*)d_out;

    const int batch = in_sizes[0] / (2 * N_IN);           // 65536
    const size_t bb_bytes = (size_t)N_IN * N_IN * 2;      // 2 MB
    const size_t o_bytes  = (size_t)batch * N_IN * 2;     // 128 MB
    const size_t p_bytes  = (size_t)4 * batch * 4;        // 1 MB

    if (ws_size >= bb_bytes + o_bytes + p_bytes) {
        __bf16* Bb     = (__bf16*)d_ws;
        __bf16* O      = (__bf16*)((char*)d_ws + bb_bytes);
        float*  part   = (float*)((char*)d_ws + bb_bytes + o_bytes);
        convB_kernel<<<(N_IN * N_IN / 4) / 256, 256, 0, stream>>>(B, Bb);
        pow_kernel<<<2048, 256, 0, stream>>>(x, alpha, O, batch * (N_IN / 8));
        qf_kernel<<<(batch / 256) * 4, NTHR, 0, stream>>>(O, Bb, A, part, batch);
        reduce_kernel<<<(batch / 4 + 255) / 256, 256, 0, stream>>>(part, C, out, batch);
    } else if (ws_size >= bb_bytes) {
        __bf16* Bb = (__bf16*)d_ws;
        convB_kernel<<<(N_IN * N_IN / 4) / 256, 256, 0, stream>>>(B, Bb);
        fused_kernel<true><<<batch / 64, NTHR, 0, stream>>>(x, A, nullptr, Bb, C, alpha, out);
    } else {
        fused_kernel<false><<<batch / 64, NTHR, 0, stream>>>(x, A, B, nullptr, C, alpha, out);
    }
}

// Round 10
// 443.109 us; speedup vs baseline: 1.0527x; 1.0527x over previous
//
#include <hip/hip_runtime.h>
#include <hip/hip_bf16.h>

typedef __bf16 bf16x8 __attribute__((ext_vector_type(8)));
typedef __bf16 bf16x4 __attribute__((ext_vector_type(4)));
typedef float  f32x4  __attribute__((ext_vector_type(4)));

#define N_IN 1024
#define NTHR 512

#define BAR() do { asm volatile("" ::: "memory"); __builtin_amdgcn_s_barrier(); \
                   asm volatile("" ::: "memory"); } while (0)

__device__ __forceinline__ void gload16(const __bf16* g, __bf16* l) {
    __builtin_amdgcn_global_load_lds(
        (const __attribute__((address_space(1))) void*)g,
        (__attribute__((address_space(3))) void*)l, 16, 0, 0);
}

// ---------- kernel 0: B (fp32) -> bf16 ----------
__global__ void convB_kernel(const float* __restrict__ B, __bf16* __restrict__ Bb) {
    int i = blockIdx.x * blockDim.x + threadIdx.x;
    f32x4 v = ((const f32x4*)B)[i];
    bf16x4 o;
    o[0] = (__bf16)v[0]; o[1] = (__bf16)v[1]; o[2] = (__bf16)v[2]; o[3] = (__bf16)v[3];
    ((bf16x4*)Bb)[i] = o;
}

// ---------- kernel 1: O = num * avg^alpha (pure streaming) ----------
__global__ __launch_bounds__(256)
void pow_kernel(const float* __restrict__ x, const float* __restrict__ alpha,
                __bf16* __restrict__ O, int nvec) {
    for (int v = blockIdx.x * blockDim.x + threadIdx.x; v < nvec;
         v += gridDim.x * blockDim.x) {
        int row = v >> 7;
        int k   = (v & 127) << 3;
        const float* xr = x + (long)row * (2 * N_IN);
        f32x4 a0 = __builtin_nontemporal_load((const f32x4*)(xr + k));
        f32x4 a1 = __builtin_nontemporal_load((const f32x4*)(xr + k + 4));
        f32x4 n0 = __builtin_nontemporal_load((const f32x4*)(xr + N_IN + k));
        f32x4 n1 = __builtin_nontemporal_load((const f32x4*)(xr + N_IN + k + 4));
        f32x4 l0 = *(const f32x4*)(alpha + k);
        f32x4 l1 = *(const f32x4*)(alpha + k + 4);
        bf16x8 w;
        #pragma unroll
        for (int e = 0; e < 4; ++e) {
            w[e]     = (__bf16)(n0[e] * __expf(l0[e] * __logf(a0[e])));
            w[e + 4] = (__bf16)(n1[e] * __expf(l1[e] * __logf(a1[e])));
        }
        __builtin_nontemporal_store(w, (bf16x8*)(O + (long)row * N_IN + k));
    }
}

// ---------- kernel 2: 8-phase-style 256x256x1024 GEMM + fused dot ----------
// Per K-tile (BK=64): 4 phases of {4 ds_read afr || stage/B-loads -> barrier ->
// 16 MFMA (setprio) -> barrier}; ONE counted vmcnt(8) per tile (4 gloads oldest,
// 8 B-loads stay in flight). A staged via global_load_lds w16, pre-swizzled src.
template<int DOSTAGE, int DOLOAD, int DOVM>
__device__ __forceinline__ void tile_step(
    const __bf16* curb, __bf16* nxtb, int TT, int kcl,
    bf16x8 (&bu0)[4], bf16x8 (&bu1)[4], bf16x8 (&bl0)[4], bf16x8 (&bl1)[4],
    f32x4 (&acc)[8][4], const __bf16* bbase, const __bf16* gsrc0,
    int wave, int rbel, int sw0, int sw1)
{
    // ---- phase 0: mh=0, kq=0 ----
    {
        bf16x8 a0 = *(const bf16x8*)(curb + rbel + 0 * 1024 + sw0);
        bf16x8 a1 = *(const bf16x8*)(curb + rbel + 1 * 1024 + sw0);
        bf16x8 a2 = *(const bf16x8*)(curb + rbel + 2 * 1024 + sw0);
        bf16x8 a3 = *(const bf16x8*)(curb + rbel + 3 * 1024 + sw0);
        if constexpr (DOSTAGE) {
            #pragma unroll
            for (int u = 0; u < 4; ++u)
                gload16(gsrc0 + (long)(wave + 8 * u) * 8 * N_IN + (TT + 1) * 64,
                        nxtb + (wave + 8 * u) * 512);
        }
        if constexpr (DOLOAD) {
            bl0[0] = *(const bf16x8*)(bbase + (long)0 * 16 * N_IN + kcl * 32);
            bl0[1] = *(const bf16x8*)(bbase + (long)1 * 16 * N_IN + kcl * 32);
        }
        BAR(); __builtin_amdgcn_sched_barrier(0);
        __builtin_amdgcn_s_setprio(1);
        #pragma unroll
        for (int n = 0; n < 4; ++n) {
            acc[0][n] = __builtin_amdgcn_mfma_f32_16x16x32_bf16(a0, bu0[n], acc[0][n], 0, 0, 0);
            acc[1][n] = __builtin_amdgcn_mfma_f32_16x16x32_bf16(a1, bu0[n], acc[1][n], 0, 0, 0);
            acc[2][n] = __builtin_amdgcn_mfma_f32_16x16x32_bf16(a2, bu0[n], acc[2][n], 0, 0, 0);
            acc[3][n] = __builtin_amdgcn_mfma_f32_16x16x32_bf16(a3, bu0[n], acc[3][n], 0, 0, 0);
        }
        __builtin_amdgcn_s_setprio(0);
        BAR();
    }
    // ---- phase 1: mh=1, kq=0 ----
    {
        bf16x8 a0 = *(const bf16x8*)(curb + rbel + 4 * 1024 + sw0);
        bf16x8 a1 = *(const bf16x8*)(curb + rbel + 5 * 1024 + sw0);
        bf16x8 a2 = *(const bf16x8*)(curb + rbel + 6 * 1024 + sw0);
        bf16x8 a3 = *(const bf16x8*)(curb + rbel + 7 * 1024 + sw0);
        if constexpr (DOLOAD) {
            bl0[2] = *(const bf16x8*)(bbase + (long)2 * 16 * N_IN + kcl * 32);
            bl0[3] = *(const bf16x8*)(bbase + (long)3 * 16 * N_IN + kcl * 32);
        }
        BAR(); __builtin_amdgcn_sched_barrier(0);
        __builtin_amdgcn_s_setprio(1);
        #pragma unroll
        for (int n = 0; n < 4; ++n) {
            acc[4][n] = __builtin_amdgcn_mfma_f32_16x16x32_bf16(a0, bu0[n], acc[4][n], 0, 0, 0);
            acc[5][n] = __builtin_amdgcn_mfma_f32_16x16x32_bf16(a1, bu0[n], acc[5][n], 0, 0, 0);
            acc[6][n] = __builtin_amdgcn_mfma_f32_16x16x32_bf16(a2, bu0[n], acc[6][n], 0, 0, 0);
            acc[7][n] = __builtin_amdgcn_mfma_f32_16x16x32_bf16(a3, bu0[n], acc[7][n], 0, 0, 0);
        }
        __builtin_amdgcn_s_setprio(0);
        BAR();
    }
    // ---- phase 2: mh=0, kq=1 ----
    {
        bf16x8 a0 = *(const bf16x8*)(curb + rbel + 0 * 1024 + sw1);
        bf16x8 a1 = *(const bf16x8*)(curb + rbel + 1 * 1024 + sw1);
        bf16x8 a2 = *(const bf16x8*)(curb + rbel + 2 * 1024 + sw1);
        bf16x8 a3 = *(const bf16x8*)(curb + rbel + 3 * 1024 + sw1);
        if constexpr (DOLOAD) {
            bl1[0] = *(const bf16x8*)(bbase + (long)0 * 16 * N_IN + (kcl + 1) * 32);
            bl1[1] = *(const bf16x8*)(bbase + (long)1 * 16 * N_IN + (kcl + 1) * 32);
        }
        BAR(); __builtin_amdgcn_sched_barrier(0);
        __builtin_amdgcn_s_setprio(1);
        #pragma unroll
        for (int n = 0; n < 4; ++n) {
            acc[0][n] = __builtin_amdgcn_mfma_f32_16x16x32_bf16(a0, bu1[n], acc[0][n], 0, 0, 0);
            acc[1][n] = __builtin_amdgcn_mfma_f32_16x16x32_bf16(a1, bu1[n], acc[1][n], 0, 0, 0);
            acc[2][n] = __builtin_amdgcn_mfma_f32_16x16x32_bf16(a2, bu1[n], acc[2][n], 0, 0, 0);
            acc[3][n] = __builtin_amdgcn_mfma_f32_16x16x32_bf16(a3, bu1[n], acc[3][n], 0, 0, 0);
        }
        __builtin_amdgcn_s_setprio(0);
        BAR();
    }
    // ---- phase 3: mh=1, kq=1 ----
    {
        bf16x8 a0 = *(const bf16x8*)(curb + rbel + 4 * 1024 + sw1);
        bf16x8 a1 = *(const bf16x8*)(curb + rbel + 5 * 1024 + sw1);
        bf16x8 a2 = *(const bf16x8*)(curb + rbel + 6 * 1024 + sw1);
        bf16x8 a3 = *(const bf16x8*)(curb + rbel + 7 * 1024 + sw1);
        if constexpr (DOLOAD) {
            bl1[2] = *(const bf16x8*)(bbase + (long)2 * 16 * N_IN + (kcl + 1) * 32);
            bl1[3] = *(const bf16x8*)(bbase + (long)3 * 16 * N_IN + (kcl + 1) * 32);
        }
        BAR(); __builtin_amdgcn_sched_barrier(0);
        __builtin_amdgcn_s_setprio(1);
        #pragma unroll
        for (int n = 0; n < 4; ++n) {
            acc[4][n] = __builtin_amdgcn_mfma_f32_16x16x32_bf16(a0, bu1[n], acc[4][n], 0, 0, 0);
            acc[5][n] = __builtin_amdgcn_mfma_f32_16x16x32_bf16(a1, bu1[n], acc[5][n], 0, 0, 0);
            acc[6][n] = __builtin_amdgcn_mfma_f32_16x16x32_bf16(a2, bu1[n], acc[6][n], 0, 0, 0);
            acc[7][n] = __builtin_amdgcn_mfma_f32_16x16x32_bf16(a3, bu1[n], acc[7][n], 0, 0, 0);
        }
        __builtin_amdgcn_s_setprio(0);
        if constexpr (DOVM) asm volatile("s_waitcnt vmcnt(8)" ::: "memory");
        BAR();
    }
}

__global__ __launch_bounds__(NTHR, 2)
void qf_kernel(const __bf16* __restrict__ O, const __bf16* __restrict__ Bb,
               const float* __restrict__ A, float* __restrict__ partial, int batch) {
    __shared__ __align__(16) __bf16 atile[2][256 * 64];   // 64 KB double-buffered
    __shared__ float rowsum[4][256];                      // 4 KB

    const int t0   = threadIdx.x;
    const int wave = t0 >> 6;
    const int lane = t0 & 63;
    const int lrow = lane & 15;
    const int lgrp = lane >> 4;
    const int wm   = wave >> 2;            // 0..1
    const int wn   = wave & 3;             // 0..3
    const int rowpanel = blockIdx.x & 255;
    const int colblk   = blockIdx.x >> 8;
    const long blk_row = (long)rowpanel * 256;
    const int colbase  = colblk * 256 + wn * 64;

    // pre-swizzled per-lane gload source (inverse of read-side (row&7)<<4 XOR)
    const __bf16* gsrc0 = O + (blk_row + (lane >> 3)) * N_IN
                            + (((lane & 7) ^ (lane >> 3)) << 3);
    const __bf16* bbase = Bb + (long)(colbase + lrow) * N_IN + lgrp * 8;
    // ds_read A addressing: element = rbel + m*1024 + (kq? sw1 : sw0)
    const int rbel = (wm * 128 + lrow) * 64;
    const int sw0  = ((lgrp ^ (lrow & 7)) << 3);
    const int sw1  = sw0 ^ 32;

    __bf16* at0 = &atile[0][0];
    __bf16* at1 = &atile[1][0];

    f32x4 acc[8][4];
    #pragma unroll
    for (int m = 0; m < 8; ++m)
        #pragma unroll
        for (int n = 0; n < 4; ++n)
            acc[m][n] = f32x4{0.f, 0.f, 0.f, 0.f};

    bf16x8 bb0[4], bb1[4], bb2[4], bb3[4];

    // ---- prologue: stage tile 0; load B kc 0,1; full drain once ----
    #pragma unroll
    for (int u = 0; u < 4; ++u)
        gload16(gsrc0 + (long)(wave + 8 * u) * 8 * N_IN, at0 + (wave + 8 * u) * 512);
    #pragma unroll
    for (int n = 0; n < 4; ++n) {
        bb0[n] = *(const bf16x8*)(bbase + (long)n * 16 * N_IN + 0 * 32);
        bb1[n] = *(const bf16x8*)(bbase + (long)n * 16 * N_IN + 1 * 32);
    }
    __syncthreads();

    // ---- 16 K-tiles: unrolled in pairs for static B-buffer naming ----
    #pragma unroll 1
    for (int t2 = 0; t2 < 14; t2 += 2) {
        tile_step<1,1,1>(at0, at1, t2,     2 * t2 + 2, bb0, bb1, bb2, bb3,
                         acc, bbase, gsrc0, wave, rbel, sw0, sw1);
        tile_step<1,1,1>(at1, at0, t2 + 1, 2 * t2 + 4, bb2, bb3, bb0, bb1,
                         acc, bbase, gsrc0, wave, rbel, sw0, sw1);
    }
    tile_step<1,1,1>(at0, at1, 14, 30, bb0, bb1, bb2, bb3,
                     acc, bbase, gsrc0, wave, rbel, sw0, sw1);
    tile_step<0,0,0>(at1, at0, 15, 0,  bb2, bb3, bb0, bb1,
                     acc, bbase, gsrc0, wave, rbel, sw0, sw1);

    // ---- epilogue: rp[r] = sum_{i in colblk} (Y[r][i] + A[i]) * o[r][i] ----
    float rp[32];
    #pragma unroll
    for (int i = 0; i < 32; ++i) rp[i] = 0.f;
    #pragma unroll
    for (int n = 0; n < 4; ++n) {
        const int i = colbase + n * 16 + lrow;
        const float Ai = A[i];
        #pragma unroll
        for (int m = 0; m < 8; ++m)
            #pragma unroll
            for (int j = 0; j < 4; ++j) {
                const long r = blk_row + wm * 128 + m * 16 + lgrp * 4 + j;
                float ov = (float)O[r * N_IN + i];   // L2/L3-hot
                rp[m * 4 + j] += (acc[m][n][j] + Ai) * ov;
            }
    }
    #pragma unroll
    for (int d = 1; d < 16; d <<= 1)
        #pragma unroll
        for (int i = 0; i < 32; ++i)
            rp[i] += __shfl_xor(rp[i], d);
    if (lrow == 0) {
        #pragma unroll
        for (int m = 0; m < 8; ++m)
            #pragma unroll
            for (int j = 0; j < 4; ++j)
                rowsum[wn][wm * 128 + m * 16 + lgrp * 4 + j] = rp[m * 4 + j];
    }
    __syncthreads();
    if (t0 < 256) {
        float s = rowsum[0][t0] + rowsum[1][t0] + rowsum[2][t0] + rowsum[3][t0];
        partial[(long)colblk * batch + blk_row + t0] = s;
    }
}

// ---------- kernel 3: out = C + sum_c partial[c] ----------
__global__ __launch_bounds__(256)
void reduce_kernel(const float* __restrict__ partial, const float* __restrict__ Cp,
                   float* __restrict__ out, int batch) {
    int b = (blockIdx.x * 256 + threadIdx.x) * 4;
    if (b >= batch) return;
    f32x4 s = *(const f32x4*)(partial + b);
    #pragma unroll
    for (int c = 1; c < 4; ++c) {
        f32x4 p = *(const f32x4*)(partial + (long)c * batch + b);
        s[0] += p[0]; s[1] += p[1]; s[2] += p[2]; s[3] += p[3];
    }
    float C = Cp[0];
    f32x4 o; o[0] = s[0] + C; o[1] = s[1] + C; o[2] = s[2] + C; o[3] = s[3] + C;
    *(f32x4*)(out + b) = o;
}

// ---------- fallback: round-2 fused kernel (used if ws too small) ----------
template<bool USEBF>
__global__ __launch_bounds__(NTHR, 2)
void fused_kernel(const float* __restrict__ x, const float* __restrict__ A,
                  const float* __restrict__ Bf, const __bf16* __restrict__ Bb,
                  const float* __restrict__ Cp, const float* __restrict__ alpha,
                  float* __restrict__ out) {
    __shared__ __align__(16) __bf16 o_panel[64 * N_IN];
    __shared__ float rowsum[8][64];
    const int t = threadIdx.x, wave = t >> 6, lane = t & 63;
    const int lrow = lane & 15, lgrp = lane >> 4;
    const long blk_row = (long)blockIdx.x * 64;
    const int srow = t >> 3, skoff = (t & 7) * 4;
    const float* xrow = x + (blk_row + srow) * (2 * N_IN);
    #pragma unroll
    for (int c = 0; c < 8; ++c) {
        int k = c * 32 + skoff;
        f32x4 sa = *(const f32x4*)(xrow + k);
        f32x4 sn = *(const f32x4*)(xrow + N_IN + k);
        f32x4 sal = *(const f32x4*)(alpha + k);
        bf16x4 w4;
        #pragma unroll
        for (int e = 0; e < 4; ++e)
            w4[e] = (__bf16)(sn[e] * __expf(sal[e] * __logf(sa[e])));
        *(bf16x4*)&o_panel[srow * N_IN + ((k & ~7) ^ ((srow & 7) << 3)) + (k & 7)] = w4;
    }
    __syncthreads();
    f32x4 acc[2][4][4];
    #pragma unroll
    for (int h = 0; h < 2; ++h)
        #pragma unroll
        for (int m = 0; m < 4; ++m)
            #pragma unroll
            for (int n = 0; n < 4; ++n)
                acc[h][m][n] = f32x4{0.f, 0.f, 0.f, 0.f};
    #pragma unroll 1
    for (int q = 0; q < 4; ++q) {
        #pragma unroll
        for (int kq = 0; kq < 8; ++kq) {
            const int kc = q * 8 + kq;
            const bool staging = (q < 3);
            const int kk = kc * 32 + lgrp * 8;
            f32x4 sa, sn, sal;
            if (staging) {
                int k = (kc + 8) * 32 + skoff;
                sa = *(const f32x4*)(xrow + k);
                sn = *(const f32x4*)(xrow + N_IN + k);
                sal = *(const f32x4*)(alpha + k);
            }
            bf16x8 afr[4];
            #pragma unroll
            for (int m = 0; m < 4; ++m) {
                int r = m * 16 + lrow;
                afr[m] = *(const bf16x8*)&o_panel[r * N_IN + (kk ^ ((r & 7) << 3))];
            }
            bf16x8 bfr[2][4];
            #pragma unroll
            for (int h = 0; h < 2; ++h)
                #pragma unroll
                for (int n = 0; n < 4; ++n) {
                    int i = h * 512 + wave * 64 + n * 16 + lrow;
                    if constexpr (USEBF) {
                        bfr[h][n] = *(const bf16x8*)&Bb[(long)i * N_IN + kk];
                    } else {
                        const float* p = Bf + (long)i * N_IN + kk;
                        f32x4 lo = *(const f32x4*)p;
                        f32x4 hi = *(const f32x4*)(p + 4);
                        #pragma unroll
                        for (int e = 0; e < 4; ++e) {
                            bfr[h][n][e] = (__bf16)lo[e];
                            bfr[h][n][e + 4] = (__bf16)hi[e];
                        }
                    }
                }
            #pragma unroll
            for (int h = 0; h < 2; ++h)
                #pragma unroll
                for (int m = 0; m < 4; ++m)
                    #pragma unroll
                    for (int n = 0; n < 4; ++n)
                        acc[h][m][n] = __builtin_amdgcn_mfma_f32_16x16x32_bf16(
                            afr[m], bfr[h][n], acc[h][m][n], 0, 0, 0);
            if (staging) {
                int k = (kc + 8) * 32 + skoff;
                bf16x4 w4;
                #pragma unroll
                for (int e = 0; e < 4; ++e)
                    w4[e] = (__bf16)(sn[e] * __expf(sal[e] * __logf(sa[e])));
                *(bf16x4*)&o_panel[srow * N_IN + ((k & ~7) ^ ((srow & 7) << 3)) + (k & 7)] = w4;
            }
        }
        __syncthreads();
    }
    float rowpart[16];
    #pragma unroll
    for (int i = 0; i < 16; ++i) rowpart[i] = 0.f;
    #pragma unroll
    for (int h = 0; h < 2; ++h)
        #pragma unroll
        for (int n = 0; n < 4; ++n) {
            int i = h * 512 + wave * 64 + n * 16 + lrow;
            float Ai = A[i];
            #pragma unroll
            for (int m = 0; m < 4; ++m)
                #pragma unroll
                for (int j = 0; j < 4; ++j) {
                    int r = m * 16 + lgrp * 4 + j;
                    float y = acc[h][m][n][j] + Ai;
                    float ov = (float)o_panel[r * N_IN + ((i & ~7) ^ ((r & 7) << 3)) + (i & 7)];
                    rowpart[m * 4 + j] += y * ov;
                }
        }
    #pragma unroll
    for (int d = 1; d < 16; d <<= 1)
        #pragma unroll
        for (int i = 0; i < 16; ++i)
            rowpart[i] += __shfl_xor(rowpart[i], d);
    if (lrow == 0) {
        #pragma unroll
        for (int m = 0; m < 4; ++m)
            #pragma unroll
            for (int j = 0; j < 4; ++j)
                rowsum[wave][m * 16 + lgrp * 4 + j] = rowpart[m * 4 + j];
    }
    __syncthreads();
    if (t < 64) {
        float s = Cp[0];
        #pragma unroll
        for (int w = 0; w < 8; ++w) s += rowsum[w][t];
        out[blk_row + t] = s;
    }
}

extern "C" void kernel_launch(void* const* d_in, const int* in_sizes, int n_in,
                              void* d_out, int out_size, void* d_ws, size_t ws_size,
                              hipStream_t stream) {
    const float* x     = (const float*)d_in[0];
    const float* A     = (const float*)d_in[1];
    const float* B     = (const float*)d_in[2];
    const float* C     = (const float*)d_in[3];
    const float* alpha = (const float*)d_in[4];
    float* out = (float*)d_out;

    const int batch = in_sizes[0] / (2 * N_IN);           // 65536
    const size_t bb_bytes = (size_t)N_IN * N_IN * 2;      // 2 MB
    const size_t o_bytes  = (size_t)batch * N_IN * 2;     // 128 MB
    const size_t p_bytes  = (size_t)4 * batch * 4;        // 1 MB

    if (ws_size >= bb_bytes + o_bytes + p_bytes) {
        __bf16* Bb   = (__bf16*)d_ws;
        __bf16* O    = (__bf16*)((char*)d_ws + bb_bytes);
        float*  part = (float*)((char*)d_ws + bb_bytes + o_bytes);
        convB_kernel<<<(N_IN * N_IN / 4) / 256, 256, 0, stream>>>(B, Bb);
        pow_kernel<<<2048, 256, 0, stream>>>(x, alpha, O, batch * (N_IN / 8));
        qf_kernel<<<(batch / 256) * 4, NTHR, 0, stream>>>(O, Bb, A, part, batch);
        reduce_kernel<<<(batch / 4 + 255) / 256, 256, 0, stream>>>(part, C, out, batch);
    } else if (ws_size >= bb_bytes) {
        __bf16* Bb = (__bf16*)d_ws;
        convB_kernel<<<(N_IN * N_IN / 4) / 256, 256, 0, stream>>>(B, Bb);
        fused_kernel<true><<<batch / 64, NTHR, 0, stream>>>(x, A, nullptr, Bb, C, alpha, out);
    } else {
        fused_kernel<false><<<batch / 64, NTHR, 0, stream>>>(x, A, B, nullptr, C, alpha, out);
    }
}